// Round 2
// baseline (151.841 us; speedup 1.0000x reference)
//
#include <hip/hip_runtime.h>
#include <math.h>

#define NB 32     // batch
#define NS 1024   // seq len
#define NT 64     // turns
#define ENC 768   // encoder dim

// Algebraic reduction of the reference (LSTM path cancels exactly):
//   scores[b,i,j] = a[b,i] + e[b,j] + fc_b, masked to j in (i, L_b)
//   lse[b,i] - s_next[b,i] = lse_j(e[b,j]) - e[b,i+1]   (a and fc_b cancel)
// so only e[b,t] = dot(enc[b, ids[b,t], :], fc_w[0, 256:1024]) is live.

// K1: e[b,t]. One 64-lane wave per (b,t); 4 waves per block.
// Gathered rows: 2048 rows x 3 KB = 6.3 MB total, coalesced float4.
__global__ void compute_e_kernel(const float* __restrict__ enc,
                                 const float* __restrict__ fc_w,
                                 const int* __restrict__ ids,
                                 float* __restrict__ e_out) {
    const int wave = threadIdx.x >> 6;
    const int lane = threadIdx.x & 63;
    const int bt = blockIdx.x * 4 + wave;     // 0..2047
    const int b = bt >> 6;
    const int idx = ids[bt];
    const float* row = enc + ((size_t)b * NS + (size_t)idx) * ENC;
    const float* we  = fc_w + 256;

    float sum = 0.f;
#pragma unroll
    for (int c = 0; c < 3; ++c) {
        const int off = (c * 64 + lane) * 4;
        const float4 x = *(const float4*)(row + off);
        const float4 w = *(const float4*)(we + off);
        sum += x.x * w.x + x.y * w.y + x.z * w.z + x.w * w.w;
    }
#pragma unroll
    for (int s = 32; s > 0; s >>= 1) sum += __shfl_xor(sum, s, 64);
    if (lane == 0) e_out[bt] = sum;
}

// K2: fully parallel loss. 2016 (b,i) rows, each an independent
//   loss[b,i] = logsumexp_{j=i+1..L_b-1}(e[b,j]) - e[b,i+1]
// One 1024-thread block; e staged in LDS (8 KB); block-reduce; single write.
__global__ void __launch_bounds__(1024)
loss_kernel(const float* __restrict__ e,
            const int* __restrict__ turn_len,
            float* __restrict__ out) {
    __shared__ float se[NB * NT];     // 8 KB
    __shared__ float red[16];
    const int tid = threadIdx.x;
    const int lane = tid & 63;
    const int wid = tid >> 6;

    // stage e into LDS, coalesced
    se[tid] = e[tid];
    se[tid + 1024] = e[tid + 1024];
    __syncthreads();

    float loss = 0.f;
#pragma unroll
    for (int pass = 0; pass < 2; ++pass) {
        const int k = tid + pass * 1024;      // (b,i) pair index
        if (k < NB * 63) {
            const int b = k / 63;
            const int i = k - b * 63;         // 0..62
            const int L = turn_len[b];
            if (i < L - 1) {
                const float* base = se + b * NT;
                float m = -INFINITY;
                for (int j = i + 1; j < L; ++j) m = fmaxf(m, base[j]);
                float s = 0.f;
                for (int j = i + 1; j < L; ++j) s += expf(base[j] - m);
                loss += m + logf(s) - base[i + 1];
            }
        }
    }

    // block reduce: wave, then cross-wave via LDS, then wave 0
#pragma unroll
    for (int s = 32; s > 0; s >>= 1) loss += __shfl_xor(loss, s, 64);
    if (lane == 0) red[wid] = loss;
    __syncthreads();
    if (wid == 0) {
        float v = (lane < 16) ? red[lane] : 0.f;
#pragma unroll
        for (int s = 32; s > 0; s >>= 1) v += __shfl_xor(v, s, 64);
        float cnt = (lane < NB) ? (float)(turn_len[lane] - 1) : 0.f;
#pragma unroll
        for (int s = 32; s > 0; s >>= 1) cnt += __shfl_xor(cnt, s, 64);
        if (lane == 0) out[0] = v / cnt;
    }
}

extern "C" void kernel_launch(void* const* d_in, const int* in_sizes, int n_in,
                              void* d_out, int out_size, void* d_ws, size_t ws_size,
                              hipStream_t stream) {
    // Inputs: 0 encoder_output | 1 W_ih | 2 W_hh | 3 b_ih | 4 b_hh
    //         5 fc_w | 6 fc_b | 7 his_turn_end_ids | 8 turn_lengths
    // LSTM path (1,2,3,4, fc_w[:256], fc_b) cancels out of the loss.
    const float* enc  = (const float*)d_in[0];
    const float* fc_w = (const float*)d_in[5];
    const int*   ids  = (const int*)d_in[7];
    const int*   tlen = (const int*)d_in[8];
    float* e = (float*)d_ws;                  // B*T floats = 8 KiB scratch

    compute_e_kernel<<<(NB * NT) / 4, 256, 0, stream>>>(enc, fc_w, ids, e);
    loss_kernel<<<1, 1024, 0, stream>>>(e, tlen, (float*)d_out);
}